// Round 3
// baseline (457.547 us; speedup 1.0000x reference)
//
#include <hip/hip_runtime.h>
#include <hip/hip_bf16.h>

#define VNUM 6890
#define KJ 24
#define NBETA 10
#define NPOSE 207
#define BATCH 1024
#define N3 20670  // VNUM*3

// d_out element offsets (f32 elements)
#define OUT_V  0
#define OUT_JT 21166080
#define OUT_J  21239808
#define OUT_RM 21313536

// ws float offsets (total ~2.03 MB — vposed lives in d_out's vertex region)
#define WS_PF   0                            // BATCH*NPOSE = 211968 floats
#define WS_A    (BATCH * NPOSE)              // BATCH*288  = 294912 floats
#define WS_JVJS (WS_A + BATCH * 288)         // KJ*33      = 792 floats

// ---------------------------------------------------------------------------
// Kernel 0: JvJs[j][0..2] = (J_reg @ v_template)[j]
//           JvJs[j][3+c*10+l] = (J_reg @ shapedirs[:,c,l])[j]
// ---------------------------------------------------------------------------
__global__ __launch_bounds__(64) void jreg_kernel(
    const float* __restrict__ Jr, const float* __restrict__ vt,
    const float* __restrict__ sd, float* __restrict__ JvJs) {
  const int j = blockIdx.x;
  const int t = threadIdx.x;
  float acc[33];
#pragma unroll
  for (int q = 0; q < 33; q++) acc[q] = 0.0f;
  for (int v = t; v < VNUM; v += 64) {
    float r = Jr[j * VNUM + v];
    const float* vtp = vt + v * 3;
    const float* sdp = sd + v * 30;
    acc[0] += r * vtp[0];
    acc[1] += r * vtp[1];
    acc[2] += r * vtp[2];
#pragma unroll
    for (int q = 0; q < 30; q++) acc[3 + q] += r * sdp[q];
  }
#pragma unroll
  for (int q = 0; q < 33; q++) {
    float x = acc[q];
    for (int off = 32; off > 0; off >>= 1) x += __shfl_down(x, off, 64);
    if (t == 0) JvJs[j * 33 + q] = x;
  }
}

// ---------------------------------------------------------------------------
// Kernel 1: per-batch: rodrigues, joints_t, pose_feature, kinematic chain, A
// ---------------------------------------------------------------------------
__global__ __launch_bounds__(64) void batch_prep(
    const float* __restrict__ body_pose, const float* __restrict__ betas,
    const float* __restrict__ global_orient, const float* __restrict__ JvJs,
    float* __restrict__ out_jt, float* __restrict__ out_j, float* __restrict__ out_rm,
    float* __restrict__ pf, float* __restrict__ Amat) {
  const int b = blockIdx.x;
  const int t = threadIdx.x;
  __shared__ float R[24][9];
  __shared__ float jt[24][3];
  __shared__ float chR[24][9];
  __shared__ float cht[24][3];

  if (t < 24) {
    float ax, ay, az;
    if (t == 0) {
      ax = global_orient[b * 3 + 0];
      ay = global_orient[b * 3 + 1];
      az = global_orient[b * 3 + 2];
    } else {
      const float* p = body_pose + (size_t)b * 69 + (t - 1) * 3;
      ax = p[0]; ay = p[1]; az = p[2];
    }
    // angle = ||aa + 1e-8|| (elementwise add, per reference); axis = aa/angle
    float px = ax + 1e-8f, py = ay + 1e-8f, pz = az + 1e-8f;
    float angle = sqrtf(px * px + py * py + pz * pz);
    float inv = 1.0f / angle;
    float rx = ax * inv, ry = ay * inv, rz = az * inv;
    float s = sinf(angle), c = cosf(angle);
    float cc = 1.0f - c;
    float m[9];
    m[0] = 1.0f - cc * (ry * ry + rz * rz);
    m[1] = -s * rz + cc * rx * ry;
    m[2] =  s * ry + cc * rx * rz;
    m[3] =  s * rz + cc * rx * ry;
    m[4] = 1.0f - cc * (rx * rx + rz * rz);
    m[5] = -s * rx + cc * ry * rz;
    m[6] = -s * ry + cc * rx * rz;
    m[7] =  s * rx + cc * ry * rz;
    m[8] = 1.0f - cc * (rx * rx + ry * ry);
#pragma unroll
    for (int e = 0; e < 9; e++) {
      R[t][e] = m[e];
      out_rm[(size_t)b * 216 + t * 9 + e] = m[e];
    }
  }
  // joints_t = Jv + Js @ betas
  for (int idx = t; idx < 72; idx += 64) {
    int j = idx / 3, c = idx % 3;
    const float* JJ = JvJs + j * 33;
    float s = JJ[c];
    const float* be = betas + (size_t)b * NBETA;
#pragma unroll
    for (int l = 0; l < NBETA; l++) s += be[l] * JJ[3 + c * 10 + l];
    jt[j][c] = s;
    out_jt[(size_t)b * 72 + idx] = s;
  }
  __syncthreads();
  // pose_feature
  for (int mI = t; mI < NPOSE; mI += 64) {
    int k = 1 + mI / 9, e = mI % 9;
    float val = R[k][e] - ((e == 0 || e == 4 || e == 8) ? 1.0f : 0.0f);
    pf[(size_t)b * NPOSE + mI] = val;
  }
  // kinematic chain (sequential; thread 0)
  if (t == 0) {
    const int par[24] = {-1, 0, 0, 0, 1, 2, 3, 4, 5, 6, 7, 8, 9, 9, 9, 12, 13, 14, 16, 17, 18, 19, 20, 21};
#pragma unroll
    for (int e = 0; e < 9; e++) chR[0][e] = R[0][e];
    cht[0][0] = jt[0][0]; cht[0][1] = jt[0][1]; cht[0][2] = jt[0][2];
    for (int k = 1; k < 24; k++) {
      int p = par[k];
      float rel0 = jt[k][0] - jt[p][0];
      float rel1 = jt[k][1] - jt[p][1];
      float rel2 = jt[k][2] - jt[p][2];
#pragma unroll
      for (int i = 0; i < 3; i++) {
        float a0 = chR[p][i * 3 + 0], a1 = chR[p][i * 3 + 1], a2 = chR[p][i * 3 + 2];
        chR[k][i * 3 + 0] = a0 * R[k][0] + a1 * R[k][3] + a2 * R[k][6];
        chR[k][i * 3 + 1] = a0 * R[k][1] + a1 * R[k][4] + a2 * R[k][7];
        chR[k][i * 3 + 2] = a0 * R[k][2] + a1 * R[k][5] + a2 * R[k][8];
        cht[k][i] = a0 * rel0 + a1 * rel1 + a2 * rel2 + cht[p][i];
      }
    }
  }
  __syncthreads();
  // A = [chR | cht - chR @ jt], joints out
  if (t < 24) {
    int k = t;
#pragma unroll
    for (int i = 0; i < 3; i++) {
      float a0 = chR[k][i * 3], a1 = chR[k][i * 3 + 1], a2 = chR[k][i * 3 + 2];
      float tr = cht[k][i] - (a0 * jt[k][0] + a1 * jt[k][1] + a2 * jt[k][2]);
      Amat[(size_t)b * 288 + k * 12 + i * 4 + 0] = a0;
      Amat[(size_t)b * 288 + k * 12 + i * 4 + 1] = a1;
      Amat[(size_t)b * 288 + k * 12 + i * 4 + 2] = a2;
      Amat[(size_t)b * 288 + k * 12 + i * 4 + 3] = tr;
      out_j[(size_t)b * 72 + k * 3 + i] = cht[k][i];
    }
  }
}

// ---------------------------------------------------------------------------
// Kernel 2: vposed[b,n] = vt[n] + betas[b]·sd[n,:] + pf[b,:]·pd[:,n]
// 64x64 f32 tile GEMM, K=207. Writes f32 into d_out's vertex region.
// ---------------------------------------------------------------------------
__global__ __launch_bounds__(256) void vposed_gemm(
    const float* __restrict__ pf, const float* __restrict__ pd,
    const float* __restrict__ vt, const float* __restrict__ sd,
    const float* __restrict__ betas, float* __restrict__ vposed) {
  __shared__ __align__(16) float As[8][64];
  __shared__ __align__(16) float Bs[8][64];
  __shared__ float betasS[64][10];
  const int bn = blockIdx.x * 64;
  const int bm = blockIdx.y * 64;
  const int tid = threadIdx.x;
  const int tx = tid & 15, ty = tid >> 4;

  for (int e = tid; e < 640; e += 256)
    betasS[e / 10][e % 10] = betas[(size_t)(bm + e / 10) * NBETA + (e % 10)];

  float acc[4][4];
#pragma unroll
  for (int i = 0; i < 4; i++)
#pragma unroll
    for (int j = 0; j < 4; j++) acc[i][j] = 0.0f;

  for (int p0 = 0; p0 < NPOSE; p0 += 8) {
    __syncthreads();
#pragma unroll
    for (int r = 0; r < 2; r++) {
      int e = tid + r * 256;
      int m = e >> 3, p = e & 7;
      int kp = p0 + p;
      As[p][m] = (kp < NPOSE) ? pf[(size_t)(bm + m) * NPOSE + kp] : 0.0f;
    }
#pragma unroll
    for (int r = 0; r < 2; r++) {
      int e = tid + r * 256;
      int n = e & 63, p = (e >> 6);
      int kp = p0 + p;
      int gn = bn + n;
      Bs[p][n] = (kp < NPOSE && gn < N3) ? pd[(size_t)kp * N3 + gn] : 0.0f;
    }
    __syncthreads();
#pragma unroll
    for (int p = 0; p < 8; p++) {
      float4 a4 = *(const float4*)&As[p][ty * 4];
      float4 b4 = *(const float4*)&Bs[p][tx * 4];
      float av[4] = {a4.x, a4.y, a4.z, a4.w};
      float bv[4] = {b4.x, b4.y, b4.z, b4.w};
#pragma unroll
      for (int i = 0; i < 4; i++)
#pragma unroll
        for (int j = 0; j < 4; j++) acc[i][j] += av[i] * bv[j];
    }
  }
  // epilogue: + vt[n] + betas·sd[n]
#pragma unroll
  for (int i = 0; i < 4; i++) {
    int mloc = ty * 4 + i;
    int m = bm + mloc;
    float bet[10];
#pragma unroll
    for (int l = 0; l < 10; l++) bet[l] = betasS[mloc][l];
#pragma unroll
    for (int j = 0; j < 4; j++) {
      int n = bn + tx * 4 + j;
      if (n < N3) {
        float s = acc[i][j] + vt[n];
#pragma unroll
        for (int l = 0; l < 10; l++) s += bet[l] * sd[(size_t)n * 10 + l];
        vposed[(size_t)m * N3 + n] = s;
      }
    }
  }
}

// ---------------------------------------------------------------------------
// Kernel 3: LBS blend: T = sum_k w[v,k] A[b,k]; vertices = T_R @ vposed + T_t
// Reads f32 vposed from the d_out vertex region and overwrites it in place
// (each element touched by exactly one thread).
// ---------------------------------------------------------------------------
__global__ __launch_bounds__(256) void blend_kernel(
    const float* __restrict__ w, const float* __restrict__ Amat,
    float* __restrict__ out_v) {
  __shared__ __align__(16) float As[8 * 288];
  const int v = blockIdx.x * 256 + threadIdx.x;
  const int b0 = blockIdx.y * 8;
  for (int e = threadIdx.x; e < 8 * 288; e += 256)
    As[e] = Amat[(size_t)b0 * 288 + e];
  __syncthreads();
  if (v >= VNUM) return;
  float wv[24];
#pragma unroll
  for (int k = 0; k < 24; k++) wv[k] = w[(size_t)v * 24 + k];
#pragma unroll 1
  for (int bb = 0; bb < 8; bb++) {
    const float4* A4 = (const float4*)&As[bb * 288];  // 72 float4 per batch
    float T0 = 0, T1 = 0, T2 = 0, T3 = 0, T4 = 0, T5 = 0;
    float T6 = 0, T7 = 0, T8 = 0, T9 = 0, T10 = 0, T11 = 0;
#pragma unroll
    for (int k = 0; k < 24; k++) {
      float wk = wv[k];
      float4 r0 = A4[k * 3 + 0];
      float4 r1 = A4[k * 3 + 1];
      float4 r2 = A4[k * 3 + 2];
      T0 += wk * r0.x; T1 += wk * r0.y; T2  += wk * r0.z; T3  += wk * r0.w;
      T4 += wk * r1.x; T5 += wk * r1.y; T6  += wk * r1.z; T7  += wk * r1.w;
      T8 += wk * r2.x; T9 += wk * r2.y; T10 += wk * r2.z; T11 += wk * r2.w;
    }
    size_t base = (size_t)(b0 + bb) * N3 + (size_t)v * 3;
    float px = out_v[base], py = out_v[base + 1], pz = out_v[base + 2];
    out_v[base + 0] = T0 * px + T1 * py + T2 * pz + T3;
    out_v[base + 1] = T4 * px + T5 * py + T6 * pz + T7;
    out_v[base + 2] = T8 * px + T9 * py + T10 * pz + T11;
  }
}

extern "C" void kernel_launch(void* const* d_in, const int* in_sizes, int n_in,
                              void* d_out, int out_size, void* d_ws, size_t ws_size,
                              hipStream_t stream) {
  const float* body_pose     = (const float*)d_in[0];
  const float* betas         = (const float*)d_in[1];
  const float* global_orient = (const float*)d_in[2];
  const float* v_template    = (const float*)d_in[3];
  const float* shapedirs     = (const float*)d_in[4];
  const float* posedirs      = (const float*)d_in[5];
  const float* J_regressor   = (const float*)d_in[6];
  const float* lbs_weights   = (const float*)d_in[7];

  float* out = (float*)d_out;
  float* out_v  = out + OUT_V;
  float* out_jt = out + OUT_JT;
  float* out_j  = out + OUT_J;
  float* out_rm = out + OUT_RM;

  float* ws = (float*)d_ws;
  float* pf   = ws + WS_PF;
  float* Amat = ws + WS_A;
  float* JvJs = ws + WS_JVJS;

  jreg_kernel<<<KJ, 64, 0, stream>>>(J_regressor, v_template, shapedirs, JvJs);
  batch_prep<<<BATCH, 64, 0, stream>>>(body_pose, betas, global_orient, JvJs,
                                       out_jt, out_j, out_rm, pf, Amat);
  vposed_gemm<<<dim3(323, 16), 256, 0, stream>>>(pf, posedirs, v_template,
                                                 shapedirs, betas, out_v);
  blend_kernel<<<dim3(27, 128), 256, 0, stream>>>(lbs_weights, Amat, out_v);
}

// Round 5
// 284.396 us; speedup vs baseline: 1.6088x; 1.6088x over previous
//
#include <hip/hip_runtime.h>
#include <hip/hip_bf16.h>

#define VNUM 6890
#define KJ 24
#define NBETA 10
#define NPOSE 207
#define KPAD 224        // NPOSE padded to 7*32
#define BATCH 1024
#define N3 20670        // VNUM*3
#define N3PAD 20672     // 323*64

// d_out element offsets (f32 elements)
#define OUT_V  0
#define OUT_JT 21166080
#define OUT_J  21239808
#define OUT_RM 21313536

// ws offsets (float units)
// JvJs:  792 floats
// Amat:  294912 floats                 -> ends 295704
// pfb:   ushort[1024*224]  = 114688 fl -> ends 410392   (round-4 bug: was counted as 57344)
// pdT:   ushort[20672*224] = 2315264 fl -> ends 2725656 (~10.4 MiB total)
#define WS_JVJS 0
#define WS_A    792
#define WS_PFB  295704
#define WS_PDT  410392

typedef unsigned short ushort;
typedef __attribute__((ext_vector_type(8))) short short8v;
typedef __attribute__((ext_vector_type(4))) float floatx4;

__device__ __forceinline__ ushort f2bfu(float x) {
  __hip_bfloat16 h = __float2bfloat16(x);
  union { __hip_bfloat16 h; ushort u; } cv; cv.h = h; return cv.u;
}

// ---------------------------------------------------------------------------
// Kernel 0: JvJs[j][0..2] = (J_reg @ v_template)[j]
//           JvJs[j][3+c*10+l] = (J_reg @ shapedirs[:,c,l])[j]
// 24 blocks x 256 threads
// ---------------------------------------------------------------------------
__global__ __launch_bounds__(256) void jreg_kernel(
    const float* __restrict__ Jr, const float* __restrict__ vt,
    const float* __restrict__ sd, float* __restrict__ JvJs) {
  const int j = blockIdx.x;
  const int t = threadIdx.x;
  const int lane = t & 63, wid = t >> 6;
  __shared__ float red[4][33];
  float acc[33];
#pragma unroll
  for (int q = 0; q < 33; q++) acc[q] = 0.0f;
  for (int v = t; v < VNUM; v += 256) {
    float r = Jr[j * VNUM + v];
    const float* vtp = vt + v * 3;
    const float* sdp = sd + v * 30;
    acc[0] += r * vtp[0];
    acc[1] += r * vtp[1];
    acc[2] += r * vtp[2];
#pragma unroll
    for (int q = 0; q < 30; q++) acc[3 + q] += r * sdp[q];
  }
#pragma unroll
  for (int q = 0; q < 33; q++) {
    float x = acc[q];
    for (int off = 32; off > 0; off >>= 1) x += __shfl_down(x, off, 64);
    if (lane == 0) red[wid][q] = x;
  }
  __syncthreads();
  if (t < 33) JvJs[j * 33 + t] = red[0][t] + red[1][t] + red[2][t] + red[3][t];
}

// ---------------------------------------------------------------------------
// Kernel 1: per-batch: rodrigues, joints_t, pose_feature(bf16), chain, A
// ---------------------------------------------------------------------------
__global__ __launch_bounds__(64) void batch_prep(
    const float* __restrict__ body_pose, const float* __restrict__ betas,
    const float* __restrict__ global_orient, const float* __restrict__ JvJs,
    float* __restrict__ out_jt, float* __restrict__ out_j, float* __restrict__ out_rm,
    ushort* __restrict__ pfb, float* __restrict__ Amat) {
  const int b = blockIdx.x;
  const int t = threadIdx.x;
  __shared__ float R[24][9];
  __shared__ float jt[24][3];
  __shared__ float chR[24][9];
  __shared__ float cht[24][3];

  if (t < 24) {
    float ax, ay, az;
    if (t == 0) {
      ax = global_orient[b * 3 + 0];
      ay = global_orient[b * 3 + 1];
      az = global_orient[b * 3 + 2];
    } else {
      const float* p = body_pose + (size_t)b * 69 + (t - 1) * 3;
      ax = p[0]; ay = p[1]; az = p[2];
    }
    float px = ax + 1e-8f, py = ay + 1e-8f, pz = az + 1e-8f;
    float angle = sqrtf(px * px + py * py + pz * pz);
    float inv = 1.0f / angle;
    float rx = ax * inv, ry = ay * inv, rz = az * inv;
    float s = sinf(angle), c = cosf(angle);
    float cc = 1.0f - c;
    float m[9];
    m[0] = 1.0f - cc * (ry * ry + rz * rz);
    m[1] = -s * rz + cc * rx * ry;
    m[2] =  s * ry + cc * rx * rz;
    m[3] =  s * rz + cc * rx * ry;
    m[4] = 1.0f - cc * (rx * rx + rz * rz);
    m[5] = -s * rx + cc * ry * rz;
    m[6] = -s * ry + cc * rx * rz;
    m[7] =  s * rx + cc * ry * rz;
    m[8] = 1.0f - cc * (rx * rx + ry * ry);
#pragma unroll
    for (int e = 0; e < 9; e++) {
      R[t][e] = m[e];
      out_rm[(size_t)b * 216 + t * 9 + e] = m[e];
    }
  }
  for (int idx = t; idx < 72; idx += 64) {
    int j = idx / 3, c = idx % 3;
    const float* JJ = JvJs + j * 33;
    float s = JJ[c];
    const float* be = betas + (size_t)b * NBETA;
#pragma unroll
    for (int l = 0; l < NBETA; l++) s += be[l] * JJ[3 + c * 10 + l];
    jt[j][c] = s;
    out_jt[(size_t)b * 72 + idx] = s;
  }
  __syncthreads();
  // pose_feature as bf16, zero-padded to KPAD
  for (int mI = t; mI < KPAD; mI += 64) {
    float val = 0.0f;
    if (mI < NPOSE) {
      int k = 1 + mI / 9, e = mI % 9;
      val = R[k][e] - ((e == 0 || e == 4 || e == 8) ? 1.0f : 0.0f);
    }
    pfb[(size_t)b * KPAD + mI] = f2bfu(val);
  }
  if (t == 0) {
    const int par[24] = {-1, 0, 0, 0, 1, 2, 3, 4, 5, 6, 7, 8, 9, 9, 9, 12, 13, 14, 16, 17, 18, 19, 20, 21};
#pragma unroll
    for (int e = 0; e < 9; e++) chR[0][e] = R[0][e];
    cht[0][0] = jt[0][0]; cht[0][1] = jt[0][1]; cht[0][2] = jt[0][2];
    for (int k = 1; k < 24; k++) {
      int p = par[k];
      float rel0 = jt[k][0] - jt[p][0];
      float rel1 = jt[k][1] - jt[p][1];
      float rel2 = jt[k][2] - jt[p][2];
#pragma unroll
      for (int i = 0; i < 3; i++) {
        float a0 = chR[p][i * 3 + 0], a1 = chR[p][i * 3 + 1], a2 = chR[p][i * 3 + 2];
        chR[k][i * 3 + 0] = a0 * R[k][0] + a1 * R[k][3] + a2 * R[k][6];
        chR[k][i * 3 + 1] = a0 * R[k][1] + a1 * R[k][4] + a2 * R[k][7];
        chR[k][i * 3 + 2] = a0 * R[k][2] + a1 * R[k][5] + a2 * R[k][8];
        cht[k][i] = a0 * rel0 + a1 * rel1 + a2 * rel2 + cht[p][i];
      }
    }
  }
  __syncthreads();
  if (t < 24) {
    int k = t;
#pragma unroll
    for (int i = 0; i < 3; i++) {
      float a0 = chR[k][i * 3], a1 = chR[k][i * 3 + 1], a2 = chR[k][i * 3 + 2];
      float tr = cht[k][i] - (a0 * jt[k][0] + a1 * jt[k][1] + a2 * jt[k][2]);
      Amat[(size_t)b * 288 + k * 12 + i * 4 + 0] = a0;
      Amat[(size_t)b * 288 + k * 12 + i * 4 + 1] = a1;
      Amat[(size_t)b * 288 + k * 12 + i * 4 + 2] = a2;
      Amat[(size_t)b * 288 + k * 12 + i * 4 + 3] = tr;
      out_j[(size_t)b * 72 + k * 3 + i] = cht[k][i];
    }
  }
}

// ---------------------------------------------------------------------------
// Kernel 2: pdT[n][k] = bf16(pd[k][n]), n in [0,N3PAD), k in [0,KPAD), zero-pad
// grid (323 n-tiles of 64, 7 k-tiles of 32), 256 threads
// ---------------------------------------------------------------------------
__global__ __launch_bounds__(256) void transpose_pd(
    const float* __restrict__ pd, ushort* __restrict__ pdT) {
  __shared__ float tile[32][65];
  const int t = threadIdx.x;
  const int n0 = blockIdx.x * 64;
  const int k0 = blockIdx.y * 32;
  const int c = t & 63;
  for (int r = t >> 6; r < 32; r += 4) {
    int k = k0 + r, n = n0 + c;
    tile[r][c] = (k < NPOSE && n < N3) ? pd[(size_t)k * N3 + n] : 0.0f;
  }
  __syncthreads();
  const int n = t >> 2;
  const int j0 = (t & 3) * 8;
  unsigned int outw[4];
#pragma unroll
  for (int jj = 0; jj < 4; jj++) {
    unsigned int lo = f2bfu(tile[j0 + jj * 2][n]);
    unsigned int hi = f2bfu(tile[j0 + jj * 2 + 1][n]);
    outw[jj] = lo | (hi << 16);
  }
  *(uint4*)&pdT[(size_t)(n0 + n) * KPAD + k0 + j0] =
      make_uint4(outw[0], outw[1], outw[2], outw[3]);
}

// ---------------------------------------------------------------------------
// Kernel 3: vposed = pf @ pd + vt + sd@betas, bf16 MFMA 16x16x32
// tile 64(m=batch) x 64(n), full K in LDS. grid (16 m, 323 n), 256 thr (4 waves)
// ---------------------------------------------------------------------------
__global__ __launch_bounds__(256) void vposed_mfma(
    const ushort* __restrict__ pfb, const ushort* __restrict__ pdT,
    const float* __restrict__ vt, const float* __restrict__ sd,
    const float* __restrict__ betas, float* __restrict__ vposed) {
  __shared__ __align__(16) ushort As[64 * KPAD];   // [m][k] 28672 B
  __shared__ __align__(16) ushort Bs[64 * KPAD];   // [n][k] 28672 B
  __shared__ float vtS[64];
  __shared__ float sdS[64][10];
  __shared__ float betS[64][10];
  const int tid = threadIdx.x;
  const int lane = tid & 63, w = tid >> 6;
  const int bm = blockIdx.x * 64;
  const int bn = blockIdx.y * 64;

  {  // stage A, B: contiguous 28672 B each = 1792 uint4
    const uint4* srcA = (const uint4*)(pfb + (size_t)bm * KPAD);
    const uint4* srcB = (const uint4*)(pdT + (size_t)bn * KPAD);
    uint4* dA = (uint4*)As;
    uint4* dB = (uint4*)Bs;
#pragma unroll
    for (int r = 0; r < 7; r++) {
      int i = tid + r * 256;
      dA[i] = srcA[i];
      dB[i] = srcB[i];
    }
    for (int e = tid; e < 64; e += 256) {
      int gn = bn + e;
      vtS[e] = (gn < N3) ? vt[gn] : 0.0f;
    }
    for (int e = tid; e < 640; e += 256) {
      int n = e / 10, l = e % 10;
      int gn = bn + n;
      sdS[n][l] = (gn < N3) ? sd[(size_t)gn * 10 + l] : 0.0f;
      betS[n][l] = betas[(size_t)(bm + n) * 10 + l];
    }
  }
  __syncthreads();

  floatx4 acc[4];
  const floatx4 zero = {0.0f, 0.0f, 0.0f, 0.0f};
#pragma unroll
  for (int ns = 0; ns < 4; ns++) acc[ns] = zero;

  const int mrow = w * 16 + (lane & 15);        // A row for this lane
  const int quad = lane >> 4;
#pragma unroll
  for (int kb = 0; kb < 7; kb++) {
    short8v av = *(const short8v*)&As[mrow * KPAD + kb * 32 + quad * 8];
#pragma unroll
    for (int ns = 0; ns < 4; ns++) {
      short8v bv = *(const short8v*)&Bs[(ns * 16 + (lane & 15)) * KPAD + kb * 32 + quad * 8];
      acc[ns] = __builtin_amdgcn_mfma_f32_16x16x32_bf16(av, bv, acc[ns], 0, 0, 0);
    }
  }

  // epilogue: C rows m = w*16 + quad*4 + reg, cols n = ns*16 + (lane&15)
  float betv[4][10];
#pragma unroll
  for (int reg = 0; reg < 4; reg++) {
    int ml = w * 16 + quad * 4 + reg;
#pragma unroll
    for (int l = 0; l < 10; l++) betv[reg][l] = betS[ml][l];
  }
#pragma unroll
  for (int ns = 0; ns < 4; ns++) {
    int nl = ns * 16 + (lane & 15);
    int gn = bn + nl;
    if (gn < N3) {
      float vtv = vtS[nl];
      float sdv[10];
#pragma unroll
      for (int l = 0; l < 10; l++) sdv[l] = sdS[nl][l];
#pragma unroll
      for (int reg = 0; reg < 4; reg++) {
        int ml = w * 16 + quad * 4 + reg;
        float s = acc[ns][reg] + vtv;
#pragma unroll
        for (int l = 0; l < 10; l++) s += betv[reg][l] * sdv[l];
        vposed[(size_t)(bm + ml) * N3 + gn] = s;
      }
    }
  }
}

// ---------------------------------------------------------------------------
// Kernel 4: LBS blend, in place on out_v
// ---------------------------------------------------------------------------
__global__ __launch_bounds__(256) void blend_kernel(
    const float* __restrict__ w, const float* __restrict__ Amat,
    float* __restrict__ out_v) {
  __shared__ __align__(16) float As[8 * 288];
  const int v = blockIdx.x * 256 + threadIdx.x;
  const int b0 = blockIdx.y * 8;
  for (int e = threadIdx.x; e < 8 * 288; e += 256)
    As[e] = Amat[(size_t)b0 * 288 + e];
  __syncthreads();
  if (v >= VNUM) return;
  float wv[24];
#pragma unroll
  for (int k = 0; k < 24; k++) wv[k] = w[(size_t)v * 24 + k];
#pragma unroll 1
  for (int bb = 0; bb < 8; bb++) {
    const float4* A4 = (const float4*)&As[bb * 288];
    float T0 = 0, T1 = 0, T2 = 0, T3 = 0, T4 = 0, T5 = 0;
    float T6 = 0, T7 = 0, T8 = 0, T9 = 0, T10 = 0, T11 = 0;
#pragma unroll
    for (int k = 0; k < 24; k++) {
      float wk = wv[k];
      float4 r0 = A4[k * 3 + 0];
      float4 r1 = A4[k * 3 + 1];
      float4 r2 = A4[k * 3 + 2];
      T0 += wk * r0.x; T1 += wk * r0.y; T2  += wk * r0.z; T3  += wk * r0.w;
      T4 += wk * r1.x; T5 += wk * r1.y; T6  += wk * r1.z; T7  += wk * r1.w;
      T8 += wk * r2.x; T9 += wk * r2.y; T10 += wk * r2.z; T11 += wk * r2.w;
    }
    size_t base = (size_t)(b0 + bb) * N3 + (size_t)v * 3;
    float px = out_v[base], py = out_v[base + 1], pz = out_v[base + 2];
    out_v[base + 0] = T0 * px + T1 * py + T2 * pz + T3;
    out_v[base + 1] = T4 * px + T5 * py + T6 * pz + T7;
    out_v[base + 2] = T8 * px + T9 * py + T10 * pz + T11;
  }
}

extern "C" void kernel_launch(void* const* d_in, const int* in_sizes, int n_in,
                              void* d_out, int out_size, void* d_ws, size_t ws_size,
                              hipStream_t stream) {
  const float* body_pose     = (const float*)d_in[0];
  const float* betas         = (const float*)d_in[1];
  const float* global_orient = (const float*)d_in[2];
  const float* v_template    = (const float*)d_in[3];
  const float* shapedirs     = (const float*)d_in[4];
  const float* posedirs      = (const float*)d_in[5];
  const float* J_regressor   = (const float*)d_in[6];
  const float* lbs_weights   = (const float*)d_in[7];

  float* out = (float*)d_out;
  float* out_v  = out + OUT_V;
  float* out_jt = out + OUT_JT;
  float* out_j  = out + OUT_J;
  float* out_rm = out + OUT_RM;

  float* ws = (float*)d_ws;
  float* JvJs = ws + WS_JVJS;
  float* Amat = ws + WS_A;
  ushort* pfb = (ushort*)(ws + WS_PFB);
  ushort* pdT = (ushort*)(ws + WS_PDT);

  jreg_kernel<<<KJ, 256, 0, stream>>>(J_regressor, v_template, shapedirs, JvJs);
  transpose_pd<<<dim3(323, 7), 256, 0, stream>>>(posedirs, pdT);
  batch_prep<<<BATCH, 64, 0, stream>>>(body_pose, betas, global_orient, JvJs,
                                       out_jt, out_j, out_rm, pfb, Amat);
  vposed_mfma<<<dim3(16, 323), 256, 0, stream>>>(pfb, pdT, v_template,
                                                 shapedirs, betas, out_v);
  blend_kernel<<<dim3(27, 128), 256, 0, stream>>>(lbs_weights, Amat, out_v);
}

// Round 6
// 258.192 us; speedup vs baseline: 1.7721x; 1.1015x over previous
//
#include <hip/hip_runtime.h>
#include <hip/hip_bf16.h>

#define VNUM 6890
#define KJ 24
#define NBETA 10
#define NPOSE 207
#define KPAD 224        // NPOSE padded to 7*32
#define BATCH 1024
#define N3 20670        // VNUM*3
#define N3PAD 20672     // 323*64

// d_out element offsets (f32 elements)
#define OUT_V  0
#define OUT_JT 21166080
#define OUT_J  21239808
#define OUT_RM 21313536

// ws offsets (float units)
#define WS_JVJS 0                 // 792 floats
#define WS_A    792               // 294912 floats -> ends 295704
#define WS_PFB  295704            // ushort[1024*224]  = 114688 floats -> ends 410392
#define WS_PDT  410392            // ushort[20672*224] = 2315264 floats -> ends 2725656

typedef unsigned short ushort;
typedef __attribute__((ext_vector_type(8))) short short8v;
typedef __attribute__((ext_vector_type(4))) float floatx4;

__device__ __forceinline__ ushort f2bfu(float x) {
  __hip_bfloat16 h = __float2bfloat16(x);
  union { __hip_bfloat16 h; ushort u; } cv; cv.h = h; return cv.u;
}

// ---------------------------------------------------------------------------
// Kernel 0: JvJs accumulation, split over 4 V-chunks, atomicAdd combine.
// JvJs[j][0..2] = (J_reg @ v_template)[j]; JvJs[j][3+c*10+l] = (J_reg @ sd[:,c,l])[j]
// ---------------------------------------------------------------------------
__global__ __launch_bounds__(256) void jreg_kernel(
    const float* __restrict__ Jr, const float* __restrict__ vt,
    const float* __restrict__ sd, float* __restrict__ JvJs) {
  const int j = blockIdx.x;
  const int chunk = blockIdx.y;
  const int t = threadIdx.x;
  const int lane = t & 63, wid = t >> 6;
  const int vbeg = chunk * 1723;
  const int vend = (vbeg + 1723 < VNUM) ? vbeg + 1723 : VNUM;
  __shared__ float red[4][33];
  float acc[33];
#pragma unroll
  for (int q = 0; q < 33; q++) acc[q] = 0.0f;
  for (int v = vbeg + t; v < vend; v += 256) {
    float r = Jr[j * VNUM + v];
    const float* vtp = vt + v * 3;
    const float* sdp = sd + v * 30;
    acc[0] += r * vtp[0];
    acc[1] += r * vtp[1];
    acc[2] += r * vtp[2];
#pragma unroll
    for (int q = 0; q < 30; q++) acc[3 + q] += r * sdp[q];
  }
#pragma unroll
  for (int q = 0; q < 33; q++) {
    float x = acc[q];
    for (int off = 32; off > 0; off >>= 1) x += __shfl_down(x, off, 64);
    if (lane == 0) red[wid][q] = x;
  }
  __syncthreads();
  if (t < 33)
    atomicAdd(&JvJs[j * 33 + t], red[0][t] + red[1][t] + red[2][t] + red[3][t]);
}

// ---------------------------------------------------------------------------
// Kernel 1: per-batch: rodrigues, joints_t, pose_feature(bf16), chain, A
// ---------------------------------------------------------------------------
__global__ __launch_bounds__(64) void batch_prep(
    const float* __restrict__ body_pose, const float* __restrict__ betas,
    const float* __restrict__ global_orient, const float* __restrict__ JvJs,
    float* __restrict__ out_jt, float* __restrict__ out_j, float* __restrict__ out_rm,
    ushort* __restrict__ pfb, float* __restrict__ Amat) {
  const int b = blockIdx.x;
  const int t = threadIdx.x;
  __shared__ float R[24][9];
  __shared__ float jt[24][3];
  __shared__ float chR[24][9];
  __shared__ float cht[24][3];

  if (t < 24) {
    float ax, ay, az;
    if (t == 0) {
      ax = global_orient[b * 3 + 0];
      ay = global_orient[b * 3 + 1];
      az = global_orient[b * 3 + 2];
    } else {
      const float* p = body_pose + (size_t)b * 69 + (t - 1) * 3;
      ax = p[0]; ay = p[1]; az = p[2];
    }
    float px = ax + 1e-8f, py = ay + 1e-8f, pz = az + 1e-8f;
    float angle = sqrtf(px * px + py * py + pz * pz);
    float inv = 1.0f / angle;
    float rx = ax * inv, ry = ay * inv, rz = az * inv;
    float s = sinf(angle), c = cosf(angle);
    float cc = 1.0f - c;
    float m[9];
    m[0] = 1.0f - cc * (ry * ry + rz * rz);
    m[1] = -s * rz + cc * rx * ry;
    m[2] =  s * ry + cc * rx * rz;
    m[3] =  s * rz + cc * rx * ry;
    m[4] = 1.0f - cc * (rx * rx + rz * rz);
    m[5] = -s * rx + cc * ry * rz;
    m[6] = -s * ry + cc * rx * rz;
    m[7] =  s * rx + cc * ry * rz;
    m[8] = 1.0f - cc * (rx * rx + ry * ry);
#pragma unroll
    for (int e = 0; e < 9; e++) {
      R[t][e] = m[e];
      out_rm[(size_t)b * 216 + t * 9 + e] = m[e];
    }
  }
  for (int idx = t; idx < 72; idx += 64) {
    int j = idx / 3, c = idx % 3;
    const float* JJ = JvJs + j * 33;
    float s = JJ[c];
    const float* be = betas + (size_t)b * NBETA;
#pragma unroll
    for (int l = 0; l < NBETA; l++) s += be[l] * JJ[3 + c * 10 + l];
    jt[j][c] = s;
    out_jt[(size_t)b * 72 + idx] = s;
  }
  __syncthreads();
  for (int mI = t; mI < KPAD; mI += 64) {
    float val = 0.0f;
    if (mI < NPOSE) {
      int k = 1 + mI / 9, e = mI % 9;
      val = R[k][e] - ((e == 0 || e == 4 || e == 8) ? 1.0f : 0.0f);
    }
    pfb[(size_t)b * KPAD + mI] = f2bfu(val);
  }
  if (t == 0) {
    const int par[24] = {-1, 0, 0, 0, 1, 2, 3, 4, 5, 6, 7, 8, 9, 9, 9, 12, 13, 14, 16, 17, 18, 19, 20, 21};
#pragma unroll
    for (int e = 0; e < 9; e++) chR[0][e] = R[0][e];
    cht[0][0] = jt[0][0]; cht[0][1] = jt[0][1]; cht[0][2] = jt[0][2];
    for (int k = 1; k < 24; k++) {
      int p = par[k];
      float rel0 = jt[k][0] - jt[p][0];
      float rel1 = jt[k][1] - jt[p][1];
      float rel2 = jt[k][2] - jt[p][2];
#pragma unroll
      for (int i = 0; i < 3; i++) {
        float a0 = chR[p][i * 3 + 0], a1 = chR[p][i * 3 + 1], a2 = chR[p][i * 3 + 2];
        chR[k][i * 3 + 0] = a0 * R[k][0] + a1 * R[k][3] + a2 * R[k][6];
        chR[k][i * 3 + 1] = a0 * R[k][1] + a1 * R[k][4] + a2 * R[k][7];
        chR[k][i * 3 + 2] = a0 * R[k][2] + a1 * R[k][5] + a2 * R[k][8];
        cht[k][i] = a0 * rel0 + a1 * rel1 + a2 * rel2 + cht[p][i];
      }
    }
  }
  __syncthreads();
  if (t < 24) {
    int k = t;
#pragma unroll
    for (int i = 0; i < 3; i++) {
      float a0 = chR[k][i * 3], a1 = chR[k][i * 3 + 1], a2 = chR[k][i * 3 + 2];
      float tr = cht[k][i] - (a0 * jt[k][0] + a1 * jt[k][1] + a2 * jt[k][2]);
      Amat[(size_t)b * 288 + k * 12 + i * 4 + 0] = a0;
      Amat[(size_t)b * 288 + k * 12 + i * 4 + 1] = a1;
      Amat[(size_t)b * 288 + k * 12 + i * 4 + 2] = a2;
      Amat[(size_t)b * 288 + k * 12 + i * 4 + 3] = tr;
      out_j[(size_t)b * 72 + k * 3 + i] = cht[k][i];
    }
  }
}

// ---------------------------------------------------------------------------
// Kernel 2: pdT[n][k] = bf16(pd[k][n])
// ---------------------------------------------------------------------------
__global__ __launch_bounds__(256) void transpose_pd(
    const float* __restrict__ pd, ushort* __restrict__ pdT) {
  __shared__ float tile[32][65];
  const int t = threadIdx.x;
  const int n0 = blockIdx.x * 64;
  const int k0 = blockIdx.y * 32;
  const int c = t & 63;
  for (int r = t >> 6; r < 32; r += 4) {
    int k = k0 + r, n = n0 + c;
    tile[r][c] = (k < NPOSE && n < N3) ? pd[(size_t)k * N3 + n] : 0.0f;
  }
  __syncthreads();
  const int n = t >> 2;
  const int j0 = (t & 3) * 8;
  unsigned int outw[4];
#pragma unroll
  for (int jj = 0; jj < 4; jj++) {
    unsigned int lo = f2bfu(tile[j0 + jj * 2][n]);
    unsigned int hi = f2bfu(tile[j0 + jj * 2 + 1][n]);
    outw[jj] = lo | (hi << 16);
  }
  *(uint4*)&pdT[(size_t)(n0 + n) * KPAD + k0 + j0] =
      make_uint4(outw[0], outw[1], outw[2], outw[3]);
}

// ---------------------------------------------------------------------------
// Kernel 3: vposed = pf @ pd + vt + sd@betas, bf16 MFMA 16x16x32
// ---------------------------------------------------------------------------
__global__ __launch_bounds__(256) void vposed_mfma(
    const ushort* __restrict__ pfb, const ushort* __restrict__ pdT,
    const float* __restrict__ vt, const float* __restrict__ sd,
    const float* __restrict__ betas, float* __restrict__ vposed) {
  __shared__ __align__(16) ushort As[64 * KPAD];
  __shared__ __align__(16) ushort Bs[64 * KPAD];
  __shared__ float vtS[64];
  __shared__ float sdS[64][10];
  __shared__ float betS[64][10];
  const int tid = threadIdx.x;
  const int lane = tid & 63, w = tid >> 6;
  const int bm = blockIdx.x * 64;
  const int bn = blockIdx.y * 64;

  {
    const uint4* srcA = (const uint4*)(pfb + (size_t)bm * KPAD);
    const uint4* srcB = (const uint4*)(pdT + (size_t)bn * KPAD);
    uint4* dA = (uint4*)As;
    uint4* dB = (uint4*)Bs;
#pragma unroll
    for (int r = 0; r < 7; r++) {
      int i = tid + r * 256;
      dA[i] = srcA[i];
      dB[i] = srcB[i];
    }
    for (int e = tid; e < 64; e += 256) {
      int gn = bn + e;
      vtS[e] = (gn < N3) ? vt[gn] : 0.0f;
    }
    for (int e = tid; e < 640; e += 256) {
      int n = e / 10, l = e % 10;
      int gn = bn + n;
      sdS[n][l] = (gn < N3) ? sd[(size_t)gn * 10 + l] : 0.0f;
      betS[n][l] = betas[(size_t)(bm + n) * 10 + l];
    }
  }
  __syncthreads();

  floatx4 acc[4];
  const floatx4 zero = {0.0f, 0.0f, 0.0f, 0.0f};
#pragma unroll
  for (int ns = 0; ns < 4; ns++) acc[ns] = zero;

  const int mrow = w * 16 + (lane & 15);
  const int quad = lane >> 4;
#pragma unroll
  for (int kb = 0; kb < 7; kb++) {
    short8v av = *(const short8v*)&As[mrow * KPAD + kb * 32 + quad * 8];
#pragma unroll
    for (int ns = 0; ns < 4; ns++) {
      short8v bv = *(const short8v*)&Bs[(ns * 16 + (lane & 15)) * KPAD + kb * 32 + quad * 8];
      acc[ns] = __builtin_amdgcn_mfma_f32_16x16x32_bf16(av, bv, acc[ns], 0, 0, 0);
    }
  }

  float betv[4][10];
#pragma unroll
  for (int reg = 0; reg < 4; reg++) {
    int ml = w * 16 + quad * 4 + reg;
#pragma unroll
    for (int l = 0; l < 10; l++) betv[reg][l] = betS[ml][l];
  }
#pragma unroll
  for (int ns = 0; ns < 4; ns++) {
    int nl = ns * 16 + (lane & 15);
    int gn = bn + nl;
    if (gn < N3) {
      float vtv = vtS[nl];
      float sdv[10];
#pragma unroll
      for (int l = 0; l < 10; l++) sdv[l] = sdS[nl][l];
#pragma unroll
      for (int reg = 0; reg < 4; reg++) {
        int ml = w * 16 + quad * 4 + reg;
        float s = acc[ns][reg] + vtv;
#pragma unroll
        for (int l = 0; l < 10; l++) s += betv[reg][l] * sdv[l];
        vposed[(size_t)(bm + ml) * N3 + gn] = s;
      }
    }
  }
}

// ---------------------------------------------------------------------------
// Kernel 4: LBS blend via MFMA. Tile: 64 vertices x 16 batches per block.
// T[b,v,0:12] = w[v,0:24] @ A[b,0:24,0:12]  (one 16x16x32 MFMA per wave/batch)
// then out[b,3v+c] = T[v,4c:4c+3]·(p,1), in place on out_v.
// Ts is per-wave private: in-order DS per wave + lgkmcnt wait, no barriers.
// ---------------------------------------------------------------------------
__global__ __launch_bounds__(256) void blend_mfma(
    const float* __restrict__ w, const float* __restrict__ Amat,
    float* __restrict__ out_v) {
  __shared__ __align__(16) ushort Ws[64 * 32];       // [v][k]  4 KB
  __shared__ __align__(16) ushort Bs[16 * 16 * 32];  // [b][n][k] 16 KB
  __shared__ __align__(16) float Ts[4][16 * 20];     // per-wave T tile, 5 KB
  const int tid = threadIdx.x;
  const int lane = tid & 63, wv = tid >> 6;
  const int quad = lane >> 4, l15 = lane & 15;
  const int v0 = blockIdx.x * 64;
  const int b0 = blockIdx.y * 16;

  // stage w -> bf16 [v][k], zero-pad k>=24 and v>=VNUM
  for (int e = tid; e < 64 * 24; e += 256) {
    int v = e / 24, k = e % 24;
    int gv = v0 + v;
    float x = (gv < VNUM) ? w[(size_t)gv * 24 + k] : 0.0f;
    Ws[v * 32 + k] = f2bfu(x);
  }
  for (int e = tid; e < 64 * 8; e += 256) {
    int v = e / 8, k = 24 + (e % 8);
    Ws[v * 32 + k] = 0;
  }
  // zero Bs then scatter-fill [b][n][k] from Amat[b][k*12+n]
  for (int e = tid; e < 4096; e += 256) ((unsigned int*)Bs)[e] = 0u;
  __syncthreads();
  for (int e = tid; e < 16 * 288; e += 256) {
    int b = e / 288, r = e - b * 288;
    int k = r / 12, n = r - k * 12;
    Bs[(b * 16 + n) * 32 + k] = f2bfu(Amat[(size_t)(b0 + b) * 288 + r]);
  }
  __syncthreads();

  // A-fragment: rows v = wv*16 + l15, k = quad*8..+7 (loaded once)
  short8v af = *(const short8v*)&Ws[(wv * 16 + l15) * 32 + quad * 8];

  // apply-phase lane mapping: lanes 0..47 -> (vertex, component)
  const int al = (lane < 48) ? lane : 0;
  const int appv = al / 3;
  const int appc = al - appv * 3;
  const int gv = v0 + wv * 16 + appv;
  const bool active = (lane < 48) && (gv < VNUM);
  float* myTs = &Ts[wv][0];

  for (int b = 0; b < 16; b++) {
    short8v bf = *(const short8v*)&Bs[(b * 16 + l15) * 32 + quad * 8];
    floatx4 acc = {0.0f, 0.0f, 0.0f, 0.0f};
    acc = __builtin_amdgcn_mfma_f32_16x16x32_bf16(af, bf, acc, 0, 0, 0);
    // C: lane holds T[v'=quad*4+reg][n=l15]
#pragma unroll
    for (int r = 0; r < 4; r++) myTs[(quad * 4 + r) * 20 + l15] = acc[r];
    __builtin_amdgcn_sched_barrier(0);
    __builtin_amdgcn_s_waitcnt(0xc07f);   // lgkmcnt(0): wave's T writes done
    __builtin_amdgcn_sched_barrier(0);
    if (active) {
      const float4 Tv = *(const float4*)&myTs[appv * 20 + appc * 4];
      size_t base = (size_t)(b0 + b) * N3 + (size_t)gv * 3;
      float px = out_v[base], py = out_v[base + 1], pz = out_v[base + 2];
      out_v[base + appc] = Tv.x * px + Tv.y * py + Tv.z * pz + Tv.w;
    }
    __builtin_amdgcn_sched_barrier(0);
  }
}

extern "C" void kernel_launch(void* const* d_in, const int* in_sizes, int n_in,
                              void* d_out, int out_size, void* d_ws, size_t ws_size,
                              hipStream_t stream) {
  const float* body_pose     = (const float*)d_in[0];
  const float* betas         = (const float*)d_in[1];
  const float* global_orient = (const float*)d_in[2];
  const float* v_template    = (const float*)d_in[3];
  const float* shapedirs     = (const float*)d_in[4];
  const float* posedirs      = (const float*)d_in[5];
  const float* J_regressor   = (const float*)d_in[6];
  const float* lbs_weights   = (const float*)d_in[7];

  float* out = (float*)d_out;
  float* out_v  = out + OUT_V;
  float* out_jt = out + OUT_JT;
  float* out_j  = out + OUT_J;
  float* out_rm = out + OUT_RM;

  float* ws = (float*)d_ws;
  float* JvJs = ws + WS_JVJS;
  float* Amat = ws + WS_A;
  ushort* pfb = (ushort*)(ws + WS_PFB);
  ushort* pdT = (ushort*)(ws + WS_PDT);

  hipMemsetAsync(JvJs, 0, KJ * 33 * sizeof(float), stream);
  jreg_kernel<<<dim3(KJ, 4), 256, 0, stream>>>(J_regressor, v_template, shapedirs, JvJs);
  transpose_pd<<<dim3(323, 7), 256, 0, stream>>>(posedirs, pdT);
  batch_prep<<<BATCH, 64, 0, stream>>>(body_pose, betas, global_orient, JvJs,
                                       out_jt, out_j, out_rm, pfb, Amat);
  vposed_mfma<<<dim3(16, 323), 256, 0, stream>>>(pfb, pdT, v_template,
                                                 shapedirs, betas, out_v);
  blend_mfma<<<dim3(108, 64), 256, 0, stream>>>(lbs_weights, Amat, out_v);
}